// Round 9
// baseline (74.259 us; speedup 1.0000x reference)
//
#include <hip/hip_runtime.h>

// P = dW/dF for W(F) = 8*tr(C) + 10*J^2 - 56*log(J) + 0.2*(I4^2 + I5^2) - 44
// C = F^T F, J = det F, G = diag(4, .5, .5), I4 = tr(C G), I5 = tr(cof(C) G)
// Analytic gradient:
//   P = 16 F + [20 J^2 - 56 + 0.8 I5^2] F^-T + 0.8 I4 * F G - 0.8 I5 * F^-T G cofC
// with F^-T = cof(F)/J, cofC = cof(C).
//
// R8: drop the OUTPUT LDS round-trip. Results go to global directly as
//     9 strided f2 stores/thread (72B stride; each wave's 9 back-to-back
//     store instrs fully cover a contiguous 4.6KB span -> L2 write-combines
//     to full lines; cached path, NOT nt). LDS ops/thread/tile: 36 -> 18.
//     Barrier B2 moved to right after the LDS->reg fill (lgkm-only, cheap),
//     so next-tile staging overlaps compute+stores. Input path unchanged:
//     coalesced f2 loads + LDS transpose + register prefetch pipeline.
//     Falsifier to watch: WRITE_SIZE amplification above ~105 MB.

typedef float f2 __attribute__((ext_vector_type(2)));

#define TPB 256
#define SAMPLES_PER_TILE 512
#define F2_PER_TILE (SAMPLES_PER_TILE * 9 / 2)   // 2304 f2 = 18 KB
#define NBLOCKS 2048

__global__ __launch_bounds__(TPB) void pk1_grad_kernel(
    const f2* __restrict__ Fin, f2* __restrict__ Pout, int total2, int ntiles)
{
    __shared__ f2 lds[F2_PER_TILE];
    const int t = threadIdx.x;

    // ---- prologue: load first tile into prefetch registers ----
    f2 pre[9];
    {
        const int base2 = blockIdx.x * F2_PER_TILE;
#pragma unroll
        for (int q = 0; q < 9; ++q) {
            int g = base2 + q * TPB + t;
            if (g < total2) pre[q] = Fin[g];
            else { pre[q].x = 1.0f; pre[q].y = 1.0f; }   // pad (discarded)
        }
    }

    for (int tile = blockIdx.x; tile < ntiles; tile += NBLOCKS) {
        const int base2 = tile * F2_PER_TILE;

        // ---- stage tile regs -> LDS (coalesced slots) ----
#pragma unroll
        for (int q = 0; q < 9; ++q) lds[q * TPB + t] = pre[q];
        __syncthreads();   // B1: tile staged

        // ---- LDS -> regs: own 2 samples, stride-9 f2 (conflict-free) ----
        float buf[18];
#pragma unroll
        for (int q = 0; q < 9; ++q) {
            f2 v = lds[t * 9 + q];
            buf[2 * q]     = v.x;
            buf[2 * q + 1] = v.y;
        }
        __syncthreads();   // B2 (lgkm-only): LDS free for next stage

        // ---- issue prefetch for tile k+1 (hides under compute+stores) ----
        const int ntile = tile + NBLOCKS;
        if (ntile < ntiles) {                 // block-uniform branch
            const int nbase2 = ntile * F2_PER_TILE;
#pragma unroll
            for (int q = 0; q < 9; ++q) {
                int g = nbase2 + q * TPB + t;
                if (g < total2) pre[q] = Fin[g];
                else { pre[q].x = 1.0f; pre[q].y = 1.0f; }
            }
        }

        // ---- compute 2 samples ----
#pragma unroll
        for (int s = 0; s < 2; ++s) {
            float f[9];
#pragma unroll
            for (int k = 0; k < 9; ++k) f[k] = buf[s * 9 + k];

            // cof(F): F^-T = cof(F)/J
            float c00 = f[4]*f[8] - f[5]*f[7];
            float c01 = f[5]*f[6] - f[3]*f[8];
            float c02 = f[3]*f[7] - f[4]*f[6];
            float c10 = f[2]*f[7] - f[1]*f[8];
            float c11 = f[0]*f[8] - f[2]*f[6];
            float c12 = f[1]*f[6] - f[0]*f[7];
            float c20 = f[1]*f[5] - f[2]*f[4];
            float c21 = f[2]*f[3] - f[0]*f[5];
            float c22 = f[0]*f[4] - f[1]*f[3];
            float J    = f[0]*c00 + f[1]*c01 + f[2]*c02;
            float invJ = 1.0f / J;

            // C = F^T F (symmetric)
            float C00 = f[0]*f[0] + f[3]*f[3] + f[6]*f[6];
            float C11 = f[1]*f[1] + f[4]*f[4] + f[7]*f[7];
            float C22 = f[2]*f[2] + f[5]*f[5] + f[8]*f[8];
            float C01 = f[0]*f[1] + f[3]*f[4] + f[6]*f[7];
            float C02 = f[0]*f[2] + f[3]*f[5] + f[6]*f[8];
            float C12 = f[1]*f[2] + f[4]*f[5] + f[7]*f[8];

            float I4 = 4.0f*C00 + 0.5f*(C11 + C22);

            // cof(C) (symmetric)
            float K00 = C11*C22 - C12*C12;
            float K11 = C00*C22 - C02*C02;
            float K22 = C00*C11 - C01*C01;
            float K01 = C02*C12 - C01*C22;
            float K02 = C01*C12 - C02*C11;
            float K12 = C01*C02 - C00*C12;

            float I5 = 4.0f*K00 + 0.5f*(K11 + K22);

            float J2    = J * J;
            float alpha = (20.0f*J2 - 56.0f + 0.8f*I5*I5) * invJ;
            float beta  = 0.8f * I4;
            float gamma = -0.8f * I5 * invJ;

            float cf[3][3] = {{c00,c01,c02},{c10,c11,c12},{c20,c21,c22}};
            float K[3][3]  = {{K00,K01,K02},{K01,K11,K12},{K02,K12,K22}};
            const float gv[3] = {4.0f, 0.5f, 0.5f};

#pragma unroll
            for (int i = 0; i < 3; ++i) {
                float a0 = cf[i][0] * 4.0f;
                float a1 = cf[i][1] * 0.5f;
                float a2 = cf[i][2] * 0.5f;
#pragma unroll
                for (int j = 0; j < 3; ++j) {
                    float M = a0 * K[0][j] + a1 * K[1][j] + a2 * K[2][j];
                    buf[s * 9 + 3 * i + j] =
                          (16.0f + beta * gv[j]) * f[3 * i + j]
                        + alpha * cf[i][j]
                        + gamma * M;
                }
            }
        }

        // ---- direct strided stores: 9 f2/thread, wave covers contiguous
        //      4.6KB span back-to-back -> L2 write-combines to full lines ----
#pragma unroll
        for (int q = 0; q < 9; ++q) {
            int g = base2 + t * 9 + q;
            if (g < total2) {
                f2 v;
                v.x = buf[2 * q];
                v.y = buf[2 * q + 1];
                Pout[g] = v;
            }
        }
        // next stage's ds_writes are safe: B2 already separated LDS reads.
    }
}

extern "C" void kernel_launch(void* const* d_in, const int* in_sizes, int n_in,
                              void* d_out, int out_size, void* d_ws, size_t ws_size,
                              hipStream_t stream) {
    const f2* F = (const f2*)d_in[0];
    f2* P = (f2*)d_out;
    int total2 = in_sizes[0] / 2;                          // 13,500,000 f2
    int ntiles = (total2 + F2_PER_TILE - 1) / F2_PER_TILE; // 5860
    pk1_grad_kernel<<<NBLOCKS, TPB, 0, stream>>>(F, P, total2, ntiles);
}

// Round 10
// 39.449 us; speedup vs baseline: 1.8824x; 1.8824x over previous
//
#include <hip/hip_runtime.h>

// P = dW/dF for W(F) = 8*tr(C) + 10*J^2 - 56*log(J) + 0.2*(I4^2 + I5^2) - 44
// C = F^T F, J = det F, G = diag(4, .5, .5), I4 = tr(C G), I5 = tr(cof(C) G)
// Analytic gradient:
//   P = 16 F + [20 J^2 - 56 + 0.8 I5^2] F^-T + 0.8 I4 * F G - 0.8 I5 * F^-T G cofC
// with F^-T = cof(F)/J, cofC = cof(C).
//
// R9: halve memory-instruction count per sample. f4 global + b128 LDS ops,
//     4 samples/thread, 1024-sample tile (2304 f4 = 36 KB), R7's 2-barrier
//     single-buffer schedule + register prefetch (R6 pipeline), 1024 blocks
//     (4/CU -- R6 proved sufficient). R8 lesson: stores MUST be coalesced
//     at wave level (strided stores = 9x TA work even when L2 merges).
//     Stride-9-f4 LDS reads: bank start (4t+4q) mod 32 -> 0 conflicts (R2).
//     Natural VGPR (R3 spill lesson).

typedef float f4 __attribute__((ext_vector_type(4)));

#define TPB 256
#define SAMPLES_PER_TILE 1024
#define F4_PER_TILE (SAMPLES_PER_TILE * 9 / 4)   // 2304 f4 = 36 KB
#define NBLOCKS 1024

__global__ __launch_bounds__(TPB) void pk1_grad_kernel(
    const f4* __restrict__ Fin, f4* __restrict__ Pout, int total4, int ntiles)
{
    __shared__ f4 lds[F4_PER_TILE];
    const int t = threadIdx.x;

    // ---- prologue: load first tile into prefetch registers ----
    f4 pre[9];
    {
        const int base4 = blockIdx.x * F4_PER_TILE;
#pragma unroll
        for (int q = 0; q < 9; ++q) {
            int g = base4 + q * TPB + t;
            if (g < total4) pre[q] = Fin[g];
            else { pre[q].x = 1.0f; pre[q].y = 0.0f; pre[q].z = 0.0f; pre[q].w = 1.0f; }
        }
    }

    for (int tile = blockIdx.x; tile < ntiles; tile += NBLOCKS) {
        const int base4 = tile * F4_PER_TILE;

        // ---- stage tile regs -> LDS (b128, coalesced slots q*TPB+t; same
        //      slots as prior store-reads by the same thread: program order) ----
#pragma unroll
        for (int q = 0; q < 9; ++q) lds[q * TPB + t] = pre[q];
        __syncthreads();   // B1: tile staged

        // ---- issue prefetch for tile k+1 (in flight during compute+store) ----
        const int ntile = tile + NBLOCKS;
        if (ntile < ntiles) {                 // block-uniform branch
            const int nbase4 = ntile * F4_PER_TILE;
#pragma unroll
            for (int q = 0; q < 9; ++q) {
                int g = nbase4 + q * TPB + t;
                if (g < total4) pre[q] = Fin[g];
                else { pre[q].x = 1.0f; pre[q].y = 0.0f; pre[q].z = 0.0f; pre[q].w = 1.0f; }
            }
        }

        // ---- LDS -> regs: own 4 samples = 9 f4 at stride 9 (conflict-free) ----
        float buf[36];
#pragma unroll
        for (int q = 0; q < 9; ++q) {
            f4 v = lds[t * 9 + q];
            buf[4 * q]     = v.x;
            buf[4 * q + 1] = v.y;
            buf[4 * q + 2] = v.z;
            buf[4 * q + 3] = v.w;
        }

        // ---- compute 4 samples ----
#pragma unroll
        for (int s = 0; s < 4; ++s) {
            float f[9];
#pragma unroll
            for (int k = 0; k < 9; ++k) f[k] = buf[s * 9 + k];

            // cof(F): F^-T = cof(F)/J
            float c00 = f[4]*f[8] - f[5]*f[7];
            float c01 = f[5]*f[6] - f[3]*f[8];
            float c02 = f[3]*f[7] - f[4]*f[6];
            float c10 = f[2]*f[7] - f[1]*f[8];
            float c11 = f[0]*f[8] - f[2]*f[6];
            float c12 = f[1]*f[6] - f[0]*f[7];
            float c20 = f[1]*f[5] - f[2]*f[4];
            float c21 = f[2]*f[3] - f[0]*f[5];
            float c22 = f[0]*f[4] - f[1]*f[3];
            float J    = f[0]*c00 + f[1]*c01 + f[2]*c02;
            float invJ = 1.0f / J;

            // C = F^T F (symmetric)
            float C00 = f[0]*f[0] + f[3]*f[3] + f[6]*f[6];
            float C11 = f[1]*f[1] + f[4]*f[4] + f[7]*f[7];
            float C22 = f[2]*f[2] + f[5]*f[5] + f[8]*f[8];
            float C01 = f[0]*f[1] + f[3]*f[4] + f[6]*f[7];
            float C02 = f[0]*f[2] + f[3]*f[5] + f[6]*f[8];
            float C12 = f[1]*f[2] + f[4]*f[5] + f[7]*f[8];

            float I4 = 4.0f*C00 + 0.5f*(C11 + C22);

            // cof(C) (symmetric)
            float K00 = C11*C22 - C12*C12;
            float K11 = C00*C22 - C02*C02;
            float K22 = C00*C11 - C01*C01;
            float K01 = C02*C12 - C01*C22;
            float K02 = C01*C12 - C02*C11;
            float K12 = C01*C02 - C00*C12;

            float I5 = 4.0f*K00 + 0.5f*(K11 + K22);

            float J2    = J * J;
            float alpha = (20.0f*J2 - 56.0f + 0.8f*I5*I5) * invJ;
            float beta  = 0.8f * I4;
            float gamma = -0.8f * I5 * invJ;

            float cf[3][3] = {{c00,c01,c02},{c10,c11,c12},{c20,c21,c22}};
            float K[3][3]  = {{K00,K01,K02},{K01,K11,K12},{K02,K12,K22}};
            const float gv[3] = {4.0f, 0.5f, 0.5f};

#pragma unroll
            for (int i = 0; i < 3; ++i) {
                float a0 = cf[i][0] * 4.0f;
                float a1 = cf[i][1] * 0.5f;
                float a2 = cf[i][2] * 0.5f;
#pragma unroll
                for (int j = 0; j < 3; ++j) {
                    float M = a0 * K[0][j] + a1 * K[1][j] + a2 * K[2][j];
                    buf[s * 9 + 3 * i + j] =
                          (16.0f + beta * gv[j]) * f[3 * i + j]
                        + alpha * cf[i][j]
                        + gamma * M;
                }
            }
        }

        // ---- results back into the SAME thread-private stride-9 slots ----
#pragma unroll
        for (int q = 0; q < 9; ++q) {
            f4 v;
            v.x = buf[4 * q];
            v.y = buf[4 * q + 1];
            v.z = buf[4 * q + 2];
            v.w = buf[4 * q + 3];
            lds[t * 9 + q] = v;
        }
        __syncthreads();   // B2: results visible; all compute-reads done

        // ---- coalesced cached stores: LDS -> global, 16B/lane ----
#pragma unroll
        for (int q = 0; q < 9; ++q) {
            int g = base4 + q * TPB + t;
            if (g < total4) Pout[g] = lds[q * TPB + t];
        }
        // loop-back stage overwrites lds[q*TPB+t] -- same thread as the
        // store above (program order), cross-thread separated by B2. Safe.
    }
}

extern "C" void kernel_launch(void* const* d_in, const int* in_sizes, int n_in,
                              void* d_out, int out_size, void* d_ws, size_t ws_size,
                              hipStream_t stream) {
    const f4* F = (const f4*)d_in[0];
    f4* P = (f4*)d_out;
    int total4 = in_sizes[0] / 4;                          // 6,750,000 f4
    int ntiles = (total4 + F4_PER_TILE - 1) / F4_PER_TILE; // 2930
    pk1_grad_kernel<<<NBLOCKS, TPB, 0, stream>>>(F, P, total4, ntiles);
}

// Round 11
// 38.544 us; speedup vs baseline: 1.9266x; 1.0235x over previous
//
#include <hip/hip_runtime.h>

// P = dW/dF for W(F) = 8*tr(C) + 10*J^2 - 56*log(J) + 0.2*(I4^2 + I5^2) - 44
// C = F^T F, J = det F, G = diag(4, .5, .5), I4 = tr(C G), I5 = tr(cof(C) G)
// Analytic gradient:
//   P = 16 F + [20 J^2 - 56 + 0.8 I5^2] F^-T + 0.8 I4 * F G - 0.8 I5 * F^-T G cofC
// with F^-T = cof(F)/J, cofC = cof(C).
//
// R10: R6 (best, 38.7us) + NON-TEMPORAL coalesced stores. Rationale:
//   input(105MB)+output(105MB) < 256MB L3, but cached output writes churn
//   L3 and evict half the input every replay (FETCH=52.7MB). nt stores
//   keep the output out of L3 -> input fully resident -> HBM traffic =
//   writes only. R1's "nt = 4x amplification" was confounded by forced
//   VGPR=32 spills (R3 proved spills alone gave WRITE=281MB); R8 proved
//   the store-merge path is sane. Here each wave store covers 4KB
//   contiguous (full lines) so nt cannot amplify partial lines.
//   Falsifier: WRITE_SIZE > 150MB or dur regression -> revert, roofline.

typedef float f2 __attribute__((ext_vector_type(2)));

#define TPB 256
#define SAMPLES_PER_TILE 512
#define F2_PER_TILE (SAMPLES_PER_TILE * 9 / 2)   // 2304 f2 = 18 KB
#define NBLOCKS 1024

__global__ __launch_bounds__(TPB) void pk1_grad_kernel(
    const f2* __restrict__ Fin, f2* __restrict__ Pout, int total2, int ntiles)
{
    __shared__ f2 ldsX[F2_PER_TILE];   // staged input tile
    __shared__ f2 ldsY[F2_PER_TILE];   // staged output tile
    const int t = threadIdx.x;

    // ---- prologue: load first tile into prefetch registers ----
    f2 pre[9];
    {
        const int base2 = blockIdx.x * F2_PER_TILE;
#pragma unroll
        for (int q = 0; q < 9; ++q) {
            int g = base2 + q * TPB + t;
            if (g < total2) pre[q] = Fin[g];
            else { pre[q].x = 1.0f; pre[q].y = 1.0f; }   // benign pad
        }
    }

    for (int tile = blockIdx.x; tile < ntiles; tile += NBLOCKS) {
        const int base2 = tile * F2_PER_TILE;

        // ---- stage current tile regs -> LDS X ----
#pragma unroll
        for (int q = 0; q < 9; ++q) ldsX[q * TPB + t] = pre[q];
        __syncthreads();   // B1: X ready

        // ---- issue prefetch for tile k+1 (in flight during compute/store) ----
        const int ntile = tile + NBLOCKS;
        if (ntile < ntiles) {                 // block-uniform branch
            const int nbase2 = ntile * F2_PER_TILE;
#pragma unroll
            for (int q = 0; q < 9; ++q) {
                int g = nbase2 + q * TPB + t;
                if (g < total2) pre[q] = Fin[g];
                else { pre[q].x = 1.0f; pre[q].y = 1.0f; }
            }
        }

        // ---- compute 2 samples from X (stride-9 f2 reads: conflict-free) ----
        float buf[18];
#pragma unroll
        for (int q = 0; q < 9; ++q) {
            f2 v = ldsX[t * 9 + q];
            buf[2 * q]     = v.x;
            buf[2 * q + 1] = v.y;
        }

#pragma unroll
        for (int s = 0; s < 2; ++s) {
            float f[9];
#pragma unroll
            for (int k = 0; k < 9; ++k) f[k] = buf[s * 9 + k];

            // cof(F): F^-T = cof(F)/J
            float c00 = f[4]*f[8] - f[5]*f[7];
            float c01 = f[5]*f[6] - f[3]*f[8];
            float c02 = f[3]*f[7] - f[4]*f[6];
            float c10 = f[2]*f[7] - f[1]*f[8];
            float c11 = f[0]*f[8] - f[2]*f[6];
            float c12 = f[1]*f[6] - f[0]*f[7];
            float c20 = f[1]*f[5] - f[2]*f[4];
            float c21 = f[2]*f[3] - f[0]*f[5];
            float c22 = f[0]*f[4] - f[1]*f[3];
            float J    = f[0]*c00 + f[1]*c01 + f[2]*c02;
            float invJ = 1.0f / J;

            // C = F^T F (symmetric)
            float C00 = f[0]*f[0] + f[3]*f[3] + f[6]*f[6];
            float C11 = f[1]*f[1] + f[4]*f[4] + f[7]*f[7];
            float C22 = f[2]*f[2] + f[5]*f[5] + f[8]*f[8];
            float C01 = f[0]*f[1] + f[3]*f[4] + f[6]*f[7];
            float C02 = f[0]*f[2] + f[3]*f[5] + f[6]*f[8];
            float C12 = f[1]*f[2] + f[4]*f[5] + f[7]*f[8];

            float I4 = 4.0f*C00 + 0.5f*(C11 + C22);

            // cof(C) (symmetric)
            float K00 = C11*C22 - C12*C12;
            float K11 = C00*C22 - C02*C02;
            float K22 = C00*C11 - C01*C01;
            float K01 = C02*C12 - C01*C22;
            float K02 = C01*C12 - C02*C11;
            float K12 = C01*C02 - C00*C12;

            float I5 = 4.0f*K00 + 0.5f*(K11 + K22);

            float J2    = J * J;
            float alpha = (20.0f*J2 - 56.0f + 0.8f*I5*I5) * invJ;
            float beta  = 0.8f * I4;
            float gamma = -0.8f * I5 * invJ;

            float cf[3][3] = {{c00,c01,c02},{c10,c11,c12},{c20,c21,c22}};
            float K[3][3]  = {{K00,K01,K02},{K01,K11,K12},{K02,K12,K22}};
            const float gv[3] = {4.0f, 0.5f, 0.5f};

#pragma unroll
            for (int i = 0; i < 3; ++i) {
                float a0 = cf[i][0] * 4.0f;
                float a1 = cf[i][1] * 0.5f;
                float a2 = cf[i][2] * 0.5f;
#pragma unroll
                for (int j = 0; j < 3; ++j) {
                    float M = a0 * K[0][j] + a1 * K[1][j] + a2 * K[2][j];
                    buf[s * 9 + 3 * i + j] =
                          (16.0f + beta * gv[j]) * f[3 * i + j]
                        + alpha * cf[i][j]
                        + gamma * M;
                }
            }
        }

        // ---- results -> LDS Y (thread-private stride-9 slots) ----
#pragma unroll
        for (int q = 0; q < 9; ++q) {
            f2 v;
            v.x = buf[2 * q];
            v.y = buf[2 * q + 1];
            ldsY[t * 9 + q] = v;
        }
        __syncthreads();   // B2: Y ready (and all X-reads of this tile done)

        // ---- coalesced NON-TEMPORAL stores: Y -> global (full lines) ----
#pragma unroll
        for (int q = 0; q < 9; ++q) {
            int g = base2 + q * TPB + t;
            if (g < total2) {
                f2 v = ldsY[q * TPB + t];
                __builtin_nontemporal_store(v, &Pout[g]);
            }
        }
        // next iteration overwrites X (disjoint from Y) then hits B1 -- safe.
    }
}

extern "C" void kernel_launch(void* const* d_in, const int* in_sizes, int n_in,
                              void* d_out, int out_size, void* d_ws, size_t ws_size,
                              hipStream_t stream) {
    const f2* F = (const f2*)d_in[0];
    f2* P = (f2*)d_out;
    int total2 = in_sizes[0] / 2;                          // 13,500,000 f2
    int ntiles = (total2 + F2_PER_TILE - 1) / F2_PER_TILE; // 5860
    pk1_grad_kernel<<<NBLOCKS, TPB, 0, stream>>>(F, P, total2, ntiles);
}